// Round 9
// baseline (585.404 us; speedup 1.0000x reference)
//
#include <hip/hip_runtime.h>
#include <stdint.h>

// Problem: BahdanauAttention  H=512, L=2, B=64, T=2048
// scores[t,b] = Wo . tanh( enc[t,b,:] @ We^T + comb[b,:] )   (bo dropped: softmax-invariant)
// comb[b,:]   = mean_l(hidden[l,b,:]) @ Wh^T + bh + be
// out[b,t]    = masked softmax over t < enc_len[b]
//
// R9: occupancy-first micro-tile GEMM. 32768 blocks x 128 thr (2 waves).
// Block tile = 32 rows x 64 cols, K=512 in 8 steps of 64. B: 8 KB/step dbuf
// glds (un-sinkable staging), one __syncthreads/step (drain is free: B(s+1)
// had a full step in flight, A-loads drain anyway). A: per-lane direct
// global->cvt->MFMA, no prefetch arrays (R6/R7/R8: compiler sinks/remats reg
// prefetch). acc=16 VGPR, launch_bounds(128,8) => VGPR<=64 tier; LDS 16KB =>
// 10 blocks/CU => 20 waves/CU (62% occ): TLP hides latency, not ILP.
// All 8 col-chunks of a 32-row group on one XCD (bid mod-8) => A re-read is
// L2-served; HBM unique = 268 MB. atomicAdd partials into zeroed scores.
//
// Workspace (1,152 KB):
//   [0, 512K)     : We packed bf16 granules: gid=((c*8+s)*8 + kk*4+jg)*64+lane
//   [512K, 640K)  : comb_t f32 [512 col][64 b]
//   [640K, 1152K) : scores f32 [64][2048]  (zeroed by prep_pack)

typedef __attribute__((ext_vector_type(4))) float f32x4;
typedef __attribute__((ext_vector_type(8))) __bf16 bf16x8;
typedef __attribute__((ext_vector_type(8))) unsigned short u16x8;

#define AS3 __attribute__((address_space(3)))
#define AS1 __attribute__((address_space(1)))

__device__ __forceinline__ float fast_tanh(float x) {
  float t = __expf(-2.0f * __builtin_fabsf(x));
  float r = (1.0f - t) * __builtin_amdgcn_rcpf(1.0f + t);
  return __builtin_copysignf(r, x);
}

// ---------------- prep 1: comb_t[o][b] = (mean_l hidden @ Wh^T + bh + be)^T --
__global__ void prep_comb_kernel(const float* __restrict__ hidden,
                                 const float* __restrict__ Wh,
                                 const float* __restrict__ bh,
                                 const float* __restrict__ be,
                                 float* __restrict__ comb_t) {
  __shared__ float hb[512];
  const int b = blockIdx.x, tid = threadIdx.x;  // 512 threads, tid = o
  hb[tid] = 0.5f * (hidden[b * 512 + tid] + hidden[32768 + b * 512 + tid]);
  __syncthreads();
  const f32x4* wr = (const f32x4*)(Wh + tid * 512);
  const f32x4* hv = (const f32x4*)hb;
  float s = 0.f;
  for (int k = 0; k < 128; ++k) {
    f32x4 w = wr[k], x = hv[k];
    s += w.x * x.x + w.y * x.y + w.z * x.z + w.w * x.w;
  }
  comb_t[tid * 64 + b] = s + bh[tid] + be[tid];
}

// ---------------- prep 2: pack We -> step-region granules; zero scores -------
// Region (c,s) (col-chunk 0..7, k-step 0..7) = 8 KB, exact LDS image:
// granule g = (kk*4 + jg)*64 + lane  ->  col = c*64 + jg*16 + (lane&15),
//                                        k   = s*64 + kk*32 + (lane>>4)*8.
__global__ void prep_pack_kernel(const float* __restrict__ We,
                                 unsigned short* __restrict__ wsw,
                                 float* __restrict__ scores) {
  const int gid = blockIdx.x * 256 + threadIdx.x;  // 0..32767
  const int reg = gid >> 9, g = gid & 511;
  const int c = reg >> 3, s = reg & 7;
  const int kk = g >> 8, jg = (g >> 6) & 3, lane = g & 63;
  const int col = c * 64 + jg * 16 + (lane & 15);
  const int k = s * 64 + kk * 32 + (lane >> 4) * 8;
  const float* src = We + col * 512 + k;
  u16x8 p;
#pragma unroll
  for (int e = 0; e < 8; ++e)
    p[e] = __builtin_bit_cast(unsigned short, (__bf16)src[e]);
  *(u16x8*)(wsw + (long)gid * 8) = p;
  ((f32x4*)scores)[gid] = (f32x4){0.f, 0.f, 0.f, 0.f};  // zero for atomics
}

// ---------------- main: micro-tile GEMM + tanh + Wo-dot ----------------------
// bid: xcd = bid&7; rest = bid>>3; chunk = rest&7; tg = xcd + (rest>>3)*8.
// rows [tg*32, +32), cols [chunk*64, +64). All 8 chunks of tg share an XCD.
__global__ __launch_bounds__(128, 8) void gemm_score_kernel(
    const float* __restrict__ enc,            // [131072, 512] (row = t*64+b)
    const unsigned short* __restrict__ wsw,   // packed We regions
    const float* __restrict__ comb_t,         // [512][64]
    const float* __restrict__ Wo,             // [512]
    float* __restrict__ scores)               // [64][2048] (atomic partials)
{
  __shared__ __align__(16) unsigned char Blds[2][8192];

  const int tid = threadIdx.x;
  const int lane = tid & 63;
  const int w = tid >> 6;         // wave: col half
  const int l15 = lane & 15;
  const int lq = lane >> 4;

  const int bid = blockIdx.x;
  const int xcd = bid & 7;
  const int rest = bid >> 3;
  const int chunk = rest & 7;
  const int tg = xcd + (rest >> 3) * 8;   // 0..4095
  const long r0 = (long)tg * 32;

  const unsigned char* breg = (const unsigned char*)wsw + (long)chunk * 65536;

#define STAGE(s, buf)                                                          \
  {                                                                            \
    const unsigned char* bs = breg + (s) * 8192 + tid * 16;                    \
    _Pragma("unroll")                                                          \
    for (int r = 0; r < 4; ++r)                                                \
      __builtin_amdgcn_global_load_lds((const AS1 unsigned int*)(bs + r * 2048), \
                                       (AS3 unsigned int*)(&Blds[buf][r * 2048 + tid * 16]), \
                                       16, 0, 0);                              \
  }

  // A base pointers (per-lane); all step/kk offsets are compile-time imms
  const float* a0 = enc + (r0 + l15) * 512 + lq * 8;
  const float* a1 = a0 + 16 * 512;

  f32x4 acc[2][2];  // [m][j], 16 VGPR
#pragma unroll
  for (int m = 0; m < 2; ++m)
#pragma unroll
    for (int j = 0; j < 2; ++j) acc[m][j] = (f32x4){0.f, 0.f, 0.f, 0.f};

  STAGE(0, 0)
  __syncthreads();  // drains glds(0)

#pragma unroll
  for (int s = 0; s < 8; ++s) {
    if (s + 1 < 8) STAGE(s + 1, (s + 1) & 1)  // overwrites buf read at s-1: safe post-barrier

#pragma unroll
    for (int kk = 0; kk < 2; ++kk) {
      const unsigned boff = (unsigned)((s & 1) * 8192 + kk * 4096 + w * 2048 + lane * 16);
      bf16x8 bf0 = *(const bf16x8*)(&Blds[0][boff]);
      bf16x8 bf1 = *(const bf16x8*)(&Blds[0][boff + 1024]);
#pragma unroll
      for (int m = 0; m < 2; ++m) {
        const float* ap = (m ? a1 : a0) + s * 64 + kk * 32;
        f32x4 va = *(const f32x4*)ap;
        f32x4 vb = *(const f32x4*)(ap + 4);
        bf16x8 af;
        af[0] = (__bf16)va.x; af[1] = (__bf16)va.y; af[2] = (__bf16)va.z; af[3] = (__bf16)va.w;
        af[4] = (__bf16)vb.x; af[5] = (__bf16)vb.y; af[6] = (__bf16)vb.z; af[7] = (__bf16)vb.w;
        acc[m][0] = __builtin_amdgcn_mfma_f32_16x16x32_bf16(af, bf0, acc[m][0], 0, 0, 0);
        acc[m][1] = __builtin_amdgcn_mfma_f32_16x16x32_bf16(af, bf1, acc[m][1], 0, 0, 0);
      }
    }
    __syncthreads();  // close step s: both waves done reading; glds(s+1) drained (free: full-step flight)
  }
#undef STAGE

  // ---- epilogue: partial Wo-dot over this block's 64 cols ----
  // D frag (16x16x32): row-in-tile = m*16 + lq*4 + q, col = chunk*64 + w*32 + j*16 + l15.
  const int trow = tg >> 1;             // scores column (t index)
  const int bbase = (tg & 1) * 32;      // b = bbase + m*16 + lq*4 + q
#pragma unroll
  for (int m = 0; m < 2; ++m) {
    float sq[4] = {0.f, 0.f, 0.f, 0.f};
#pragma unroll
    for (int j = 0; j < 2; ++j) {
      const int col = chunk * 64 + w * 32 + j * 16 + l15;
      const float wo = Wo[col];
      const f32x4 ct = *(const f32x4*)(comb_t + col * 64 + bbase + m * 16 + lq * 4);
#pragma unroll
      for (int q = 0; q < 4; ++q)
        sq[q] += fast_tanh(acc[m][j][q] + ct[q]) * wo;
    }
#pragma unroll
    for (int q = 0; q < 4; ++q) {
      float v = sq[q];
      v += __shfl_xor(v, 1, 16);
      v += __shfl_xor(v, 2, 16);
      v += __shfl_xor(v, 4, 16);
      v += __shfl_xor(v, 8, 16);
      if (l15 == 0) {
        const int b = bbase + m * 16 + lq * 4 + q;
        atomicAdd(scores + (long)b * 2048 + trow, v);
      }
    }
  }
}

// ---------------- masked softmax over valid prefix ---------------------------
__global__ void softmax_kernel(const float* __restrict__ scores,
                               const int* __restrict__ enc_len,
                               float* __restrict__ out) {
  const int b = blockIdx.x;
  const int tid = threadIdx.x;  // 256
  const int lane = tid & 63;
  const int wv = tid >> 6;
  __shared__ float red[4];
  const int n = enc_len[b];
  const float* sc = scores + (long)b * 2048;

  float v[8];
  float m = -1e30f;
#pragma unroll
  for (int j = 0; j < 8; ++j) {
    const int t = tid + j * 256;
    v[j] = sc[t];
    if (t < n) m = fmaxf(m, v[j]);
  }
#pragma unroll
  for (int k = 32; k; k >>= 1) m = fmaxf(m, __shfl_xor(m, k, 64));
  if (lane == 0) red[wv] = m;
  __syncthreads();
  m = fmaxf(fmaxf(red[0], red[1]), fmaxf(red[2], red[3]));
  __syncthreads();

  float s = 0.f;
#pragma unroll
  for (int j = 0; j < 8; ++j) {
    const int t = tid + j * 256;
    const float e = (t < n) ? __expf(v[j] - m) : 0.f;
    v[j] = e;
    s += e;
  }
#pragma unroll
  for (int k = 32; k; k >>= 1) s += __shfl_xor(s, k, 64);
  if (lane == 0) red[wv] = s;
  __syncthreads();
  s = red[0] + red[1] + red[2] + red[3];
  const float inv = 1.0f / s;
#pragma unroll
  for (int j = 0; j < 8; ++j) {
    const int t = tid + j * 256;
    out[(long)b * 2048 + t] = v[j] * inv;
  }
}

extern "C" void kernel_launch(void* const* d_in, const int* in_sizes, int n_in,
                              void* d_out, int out_size, void* d_ws, size_t ws_size,
                              hipStream_t stream) {
  const float* hidden = (const float*)d_in[0];   // [2,64,512]
  const float* enc    = (const float*)d_in[1];   // [2048,64,512]
  const int*   enclen = (const int*)d_in[2];     // [64]
  const float* Wh     = (const float*)d_in[3];   // [512,512]
  const float* bh     = (const float*)d_in[4];   // [512]
  const float* We     = (const float*)d_in[5];   // [512,512]
  const float* be     = (const float*)d_in[6];   // [512]
  const float* Wo     = (const float*)d_in[7];   // [512]
  // d_in[8] = bo: softmax-invariant, dropped
  float* out = (float*)d_out;

  uint8_t* ws = (uint8_t*)d_ws;
  unsigned short* wsw = (unsigned short*)ws;             // 512 KB packed We
  float* comb_t = (float*)(ws + 524288);                 // 128 KB [512][64]
  float* scores = (float*)(ws + 524288 + 131072);        // 512 KB

  hipLaunchKernelGGL(prep_comb_kernel, dim3(64), dim3(512), 0, stream,
                     hidden, Wh, bh, be, comb_t);
  hipLaunchKernelGGL(prep_pack_kernel, dim3(128), dim3(256), 0, stream,
                     We, wsw, scores);
  hipLaunchKernelGGL(gemm_score_kernel, dim3(32768), dim3(128), 0, stream,
                     enc, wsw, comb_t, Wo, scores);
  hipLaunchKernelGGL(softmax_kernel, dim3(64), dim3(256), 0, stream,
                     scores, enclen, out);
}

// Round 10
// 165.345 us; speedup vs baseline: 3.5405x; 3.5405x over previous
//
#include <hip/hip_runtime.h>
#include <stdint.h>

// Problem: BahdanauAttention  H=512, L=2, B=64, T=2048
// scores[t,b] = Wo . tanh( enc[t,b,:] @ We^T + comb[b,:] )   (bo dropped: softmax-invariant)
// comb[b,:]   = mean_l(hidden[l,b,:]) @ Wh^T + bh + be
// out[b,t]    = masked softmax over t < enc_len[b]
//
// R10 = R2 geometry (BM=64, BK=32, dbuf, 73KB LDS, 2 blocks/CU) + counted-wait
// schedule: per step STAGE B(s+1) -> vmcnt(4) (retires B(s)/A(s+1), full-step
// flight; keeps B(s+1) in flight) -> cvt A(s+1)->LDS -> issue A(s+2) regs ->
// ds_read+MFMA(setprio) -> lgkm-ONLY barrier (never drains vmcnt). Two
// anti-phase resident blocks keep the per-CU vmem queue full.
//
// Workspace (1,152 KB):
//   [0, 512K)            : We packed bf16, 16 K-slices of 32KB, swizzled LDS image
//   [512K, 512K+128K)    : comb f32 [64][512]
//   [640K, 640K+512K)    : scores f32 [64][2048]  (b-major for softmax)

typedef __attribute__((ext_vector_type(4))) float f32x4;
typedef __attribute__((ext_vector_type(8))) __bf16 bf16x8;
typedef __attribute__((ext_vector_type(8))) unsigned short u16x8;
typedef __attribute__((ext_vector_type(4))) unsigned short u16x4;

#define AS3 __attribute__((address_space(3)))
#define AS1 __attribute__((address_space(1)))

__device__ __forceinline__ unsigned short f2bf(float f) {
  unsigned u = __builtin_bit_cast(unsigned, f);
  return (unsigned short)((u + 0x7FFFu + ((u >> 16) & 1u)) >> 16);  // RNE
}

__device__ __forceinline__ float fast_tanh(float x) {
  float t = __expf(-2.0f * __builtin_fabsf(x));
  float r = (1.0f - t) * __builtin_amdgcn_rcpf(1.0f + t);
  return __builtin_copysignf(r, x);
}

#define SB() __builtin_amdgcn_sched_barrier(0)

#define VMWAIT(n) do { \
  asm volatile("s_waitcnt vmcnt(" #n ")" ::: "memory"); \
  __builtin_amdgcn_sched_barrier(0); \
} while (0)

// lgkmcnt(0)-only barrier: publishes ds ops without draining vmcnt.
#define WAVE_SYNC() do { \
  asm volatile("s_waitcnt lgkmcnt(0)" ::: "memory"); \
  __builtin_amdgcn_s_barrier(); \
  __builtin_amdgcn_sched_barrier(0); \
} while (0)

// ---------------- prep 1: comb[b,o] = mean_l hidden @ Wh^T + bh + be ----------
__global__ void prep_comb_kernel(const float* __restrict__ hidden,
                                 const float* __restrict__ Wh,
                                 const float* __restrict__ bh,
                                 const float* __restrict__ be,
                                 float* __restrict__ comb) {
  __shared__ float hb[512];
  const int b = blockIdx.x, tid = threadIdx.x;  // 256 threads
  for (int i = tid; i < 512; i += 256)
    hb[i] = 0.5f * (hidden[b * 512 + i] + hidden[32768 + b * 512 + i]);
  __syncthreads();
  for (int o = tid; o < 512; o += 256) {
    const f32x4* wr = (const f32x4*)(Wh + o * 512);
    const f32x4* hv = (const f32x4*)hb;
    float s = 0.f;
    for (int k = 0; k < 128; ++k) {
      f32x4 w = wr[k], x = hv[k];
      s += w.x * x.x + w.y * x.y + w.z * x.z + w.w * x.w;
    }
    comb[b * 512 + o] = s + bh[o] + be[o];
  }
}

// ---------------- prep 2: pack We -> bf16 swizzled K-slice LDS images --------
// Slice s (k0 = s*32) is a 32KB image. Granule (16B) for (o, g) lives at
// granule index  o*4 + ((g ^ (o>>1)) & 3),  content = bf16(We[o][k0+g*8 .. +8])
__global__ void prep_pack_kernel(const float* __restrict__ We,
                                 unsigned short* __restrict__ wsw) {
  const int gid = blockIdx.x * 256 + threadIdx.x;  // 0..32767 granules
  const int s = gid >> 11;
  const int rem = gid & 2047;
  const int o = rem >> 2;
  const int g = rem & 3;
  const float* src = We + o * 512 + s * 32 + g * 8;
  u16x8 p;
#pragma unroll
  for (int e = 0; e < 8; ++e) p[e] = f2bf(src[e]);
  const int dgran = s * 2048 + o * 4 + ((g ^ (o >> 1)) & 3);
  *(u16x8*)(wsw + (long)dgran * 8) = p;
}

// ---------------- main: fused GEMM + tanh + Wo-dot -> scores -----------------
// grid 2048 (one block per t), 512 threads (8 waves: wm in {0,1}, wn in {0..3})
// block tile 64 x 512, BK=32 (16 steps), dbuf A+B, 2 blocks/CU.
__global__ __launch_bounds__(512, 4) void gemm_score_kernel(
    const float* __restrict__ enc,            // [T*B, 512] (row = t*64+b)
    const unsigned short* __restrict__ wsw,   // packed We (16 slices x 32KB)
    const float* __restrict__ comb,           // [64,512]
    const float* __restrict__ Wo,             // [512]
    float* __restrict__ scores)               // [64,2048]
{
  __shared__ __align__(16) unsigned char Blds[2][32768];  // 512 o x 32 k bf16 (swz)
  __shared__ __align__(16) unsigned char Alds[2][4096];   // 64 r x 32 k bf16 (swz)
  __shared__ float spart[4][64];

  const int tid = threadIdx.x;
  const int lane = tid & 63;
  const int wave = tid >> 6;
  const int wm = wave >> 2;   // row half (32 rows each)
  const int wn = wave & 3;    // col quarter (128 cols each)
  const int l15 = lane & 15;
  const int lq = lane >> 4;   // k-granule 0..3

  const long r0 = (long)blockIdx.x * 64;

  // A staging: thread -> row = tid>>3, 4-float chunk c4 = tid&7
  const int arow = tid >> 3;
  const int ac4 = tid & 7;
  const float* aglb = enc + (r0 + arow) * 512 + ac4 * 4;
  const unsigned awoff = (unsigned)(arow * 64 +
                         ((((ac4 >> 1) ^ (arow >> 1)) & 3) << 4) + (ac4 & 1) * 8);

  const unsigned char* bglb = (const unsigned char*)wsw + (long)tid * 16;

  // fragment read offsets (2-way-max swizzled: free)
  const unsigned swz = (unsigned)(((lq ^ (l15 >> 1)) & 3) << 4);
  const unsigned aoff = (unsigned)((wm * 32 + l15) * 64) + swz;   // + m*1024
  const unsigned boff = (unsigned)((wn * 128 + l15) * 64) + swz;  // + jn*1024

  f32x4 acc[2][8];
#pragma unroll
  for (int m = 0; m < 2; ++m)
#pragma unroll
    for (int j = 0; j < 8; ++j) acc[m][j] = (f32x4){0.f, 0.f, 0.f, 0.f};

#define STAGE_B(n)                                                             \
  {                                                                            \
    const unsigned char* bs_ = bglb + (long)(n) * 32768;                       \
    _Pragma("unroll")                                                          \
    for (int c = 0; c < 4; ++c)                                                \
      __builtin_amdgcn_global_load_lds((const AS1 unsigned int*)(bs_ + c * 8192), \
                                       (AS3 unsigned int*)(&Blds[(n) & 1][tid * 16 + c * 8192]), \
                                       16, 0, 0);                              \
  }

#define CVT_A(v, buf)                                                          \
  {                                                                            \
    u16x4 p_;                                                                  \
    p_[0] = f2bf((v).x); p_[1] = f2bf((v).y);                                  \
    p_[2] = f2bf((v).z); p_[3] = f2bf((v).w);                                  \
    *(u16x4*)(&Alds[buf][awoff]) = p_;                                         \
  }

  f32x4 apre[2];  // apre[(s+1)&1] holds A(s+1) regs at step s

  // ---- prologue: B(0) staged+drained, A(0) in LDS, B(1)/A(1) left in flight --
  STAGE_B(0)
  f32x4 ra0 = *(const f32x4*)(aglb);           // A(0)
  apre[1] = *(const f32x4*)(aglb + 32);        // A(1)
  SB();
  VMWAIT(0);                                   // prologue-only full drain
  CVT_A(ra0, 0)
  WAVE_SYNC();                                 // publish Alds[0]; Blds[0] ready

  // ---- main loop: 16 K-steps ----
#pragma unroll
  for (int ks = 0; ks < 16; ++ks) {
    // 1. stage B(ks+1) (glds, un-sinkable)
    if (ks + 1 < 16) STAGE_B(ks + 1)
    SB();
    // 2. counted wait: retire B(ks) + A(ks+1) (full-step flight); keep B(ks+1)
    if (ks + 1 < 16) VMWAIT(4); else VMWAIT(0);
    // 3. cvt A(ks+1) -> Alds[(ks+1)&1]; issue A(ks+2) regs
    if (ks + 1 < 16) CVT_A(apre[(ks + 1) & 1], (ks + 1) & 1)
    if (ks + 2 < 16) apre[ks & 1] = *(const f32x4*)(aglb + (ks + 2) * 32);
    SB();
    // 4. compute on Alds[ks&1], Blds[ks&1]
    bf16x8 af0 = *(const bf16x8*)(&Alds[ks & 1][aoff]);
    bf16x8 af1 = *(const bf16x8*)(&Alds[ks & 1][aoff + 1024]);
    __builtin_amdgcn_s_setprio(1);
#pragma unroll
    for (int jn = 0; jn < 8; ++jn) {
      bf16x8 bf = *(const bf16x8*)(&Blds[ks & 1][boff + jn * 1024]);
      acc[0][jn] = __builtin_amdgcn_mfma_f32_16x16x32_bf16(af0, bf, acc[0][jn], 0, 0, 0);
      acc[1][jn] = __builtin_amdgcn_mfma_f32_16x16x32_bf16(af1, bf, acc[1][jn], 0, 0, 0);
    }
    __builtin_amdgcn_s_setprio(0);
    // 5. lgkm-only barrier: publishes Alds writes, drains ds_reads; vmcnt alive
    WAVE_SYNC();
  }
#undef STAGE_B
#undef CVT_A

  // ---- fused epilogue: tanh(acc + comb[b,col]) * Wo[col], reduce over cols ----
  // D frag: row = wm*32 + m*16 + lq*4 + q (== b), col = wn*128 + jn*16 + l15.
  float wo[8];
#pragma unroll
  for (int jn = 0; jn < 8; ++jn) wo[jn] = Wo[wn * 128 + jn * 16 + l15];

  float ps[2][4];
#pragma unroll
  for (int m = 0; m < 2; ++m) {
#pragma unroll
    for (int q = 0; q < 4; ++q) {
      const int row = wm * 32 + m * 16 + lq * 4 + q;  // == b
      const float* crow = comb + row * 512;
      float s = 0.f;
#pragma unroll
      for (int jn = 0; jn < 8; ++jn) {
        const int col = wn * 128 + jn * 16 + l15;
        const float x = acc[m][jn][q] + crow[col];
        s += fast_tanh(x) * wo[jn];
      }
      ps[m][q] = s;
    }
  }
#pragma unroll
  for (int m = 0; m < 2; ++m)
#pragma unroll
    for (int q = 0; q < 4; ++q) {
      float s = ps[m][q];
      s += __shfl_xor(s, 1, 16);
      s += __shfl_xor(s, 2, 16);
      s += __shfl_xor(s, 4, 16);
      s += __shfl_xor(s, 8, 16);
      if (l15 == 0) spart[wn][wm * 32 + m * 16 + lq * 4 + q] = s;
    }
  __syncthreads();
  if (tid < 64) {
    float s = spart[0][tid] + spart[1][tid] + spart[2][tid] + spart[3][tid];
    scores[(long)tid * 2048 + blockIdx.x] = s;  // scores[b][t], t = blockIdx
  }
}

// ---------------- masked softmax over valid prefix ---------------------------
__global__ void softmax_kernel(const float* __restrict__ scores,
                               const int* __restrict__ enc_len,
                               float* __restrict__ out) {
  const int b = blockIdx.x;
  const int tid = threadIdx.x;  // 256
  const int lane = tid & 63;
  const int wv = tid >> 6;
  __shared__ float red[4];
  const int n = enc_len[b];
  const float* sc = scores + (long)b * 2048;

  float v[8];
  float m = -1e30f;
#pragma unroll
  for (int j = 0; j < 8; ++j) {
    const int t = tid + j * 256;
    v[j] = sc[t];
    if (t < n) m = fmaxf(m, v[j]);
  }
#pragma unroll
  for (int k = 32; k; k >>= 1) m = fmaxf(m, __shfl_xor(m, k, 64));
  if (lane == 0) red[wv] = m;
  __syncthreads();
  m = fmaxf(fmaxf(red[0], red[1]), fmaxf(red[2], red[3]));
  __syncthreads();

  float s = 0.f;
#pragma unroll
  for (int j = 0; j < 8; ++j) {
    const int t = tid + j * 256;
    const float e = (t < n) ? __expf(v[j] - m) : 0.f;
    v[j] = e;
    s += e;
  }
#pragma unroll
  for (int k = 32; k; k >>= 1) s += __shfl_xor(s, k, 64);
  if (lane == 0) red[wv] = s;
  __syncthreads();
  s = red[0] + red[1] + red[2] + red[3];
  const float inv = 1.0f / s;
#pragma unroll
  for (int j = 0; j < 8; ++j) {
    const int t = tid + j * 256;
    out[(long)b * 2048 + t] = v[j] * inv;
  }
}

extern "C" void kernel_launch(void* const* d_in, const int* in_sizes, int n_in,
                              void* d_out, int out_size, void* d_ws, size_t ws_size,
                              hipStream_t stream) {
  const float* hidden = (const float*)d_in[0];   // [2,64,512]
  const float* enc    = (const float*)d_in[1];   // [2048,64,512]
  const int*   enclen = (const int*)d_in[2];     // [64]
  const float* Wh     = (const float*)d_in[3];   // [512,512]
  const float* bh     = (const float*)d_in[4];   // [512]
  const float* We     = (const float*)d_in[5];   // [512,512]
  const float* be     = (const float*)d_in[6];   // [512]
  const float* Wo     = (const float*)d_in[7];   // [512]
  // d_in[8] = bo: softmax-invariant, dropped
  float* out = (float*)d_out;

  uint8_t* ws = (uint8_t*)d_ws;
  unsigned short* wsw = (unsigned short*)ws;             // 512 KB
  float* comb   = (float*)(ws + 524288);                 // 128 KB
  float* scores = (float*)(ws + 524288 + 131072);        // 512 KB

  hipLaunchKernelGGL(prep_comb_kernel, dim3(64), dim3(256), 0, stream,
                     hidden, Wh, bh, be, comb);
  hipLaunchKernelGGL(prep_pack_kernel, dim3(128), dim3(256), 0, stream, We, wsw);
  hipLaunchKernelGGL(gemm_score_kernel, dim3(2048), dim3(512), 0, stream,
                     enc, wsw, comb, Wo, scores);
  hipLaunchKernelGGL(softmax_kernel, dim3(64), dim3(256), 0, stream,
                     scores, enclen, out);
}

// Round 11
// 159.298 us; speedup vs baseline: 3.6749x; 1.0380x over previous
//
#include <hip/hip_runtime.h>
#include <stdint.h>

// Problem: BahdanauAttention  H=512, L=2, B=64, T=2048
// scores[t,b] = Wo . tanh( enc[t,b,:] @ We^T + comb[b,:] )   (bo dropped: softmax-invariant)
// comb[b,:]   = mean_l(hidden[l,b,:]) @ Wh^T + bh + be
// out[b,t]    = masked softmax over t < enc_len[b]
//
// R11: 8-phase-template port (T3+T4+T5). BM=128, BN=512, BK=64 -> 8 K-steps,
// 4 phases/step of {barrier; ds_read subtile; lgkm(0); setprio; 16 MFMA}.
// Step top: issue B(t+1) 8 glds -> VMWAIT(8) (retires B(t)+A(t+1) regs, full
// step flight; B(t+1) spans all 4 phase barriers) -> cvt A(t+1)->LDS ->
// issue A(t+2) regs -> lgkm(0). Prologue VMWAIT(12), tail VMWAIT(0).
// LDS: B dbuf 2x64KB + A dbuf 2x16KB = 160 KiB exact. acc[4][8] AGPR,
// 1 block/CU, 2 waves/SIMD (phase role-split makes setprio pay).
//
// Workspace (1,152 KB):
//   [0, 512K)     : We packed bf16, 8 K-slices of 64KB, XOR-8 swizzled image
//   [512K, 640K)  : comb f32 [64][512]
//   [640K, 1152K) : scores f32 [64][2048]

typedef __attribute__((ext_vector_type(4))) float f32x4;
typedef __attribute__((ext_vector_type(8))) __bf16 bf16x8;
typedef __attribute__((ext_vector_type(8))) unsigned short u16x8;

#define AS3 __attribute__((address_space(3)))
#define AS1 __attribute__((address_space(1)))

__device__ __forceinline__ unsigned short f2bf(float f) {
  return __builtin_bit_cast(unsigned short, (__bf16)f);
}

__device__ __forceinline__ float fast_tanh(float x) {
  float t = __expf(-2.0f * __builtin_fabsf(x));
  float r = (1.0f - t) * __builtin_amdgcn_rcpf(1.0f + t);
  return __builtin_copysignf(r, x);
}

#define SB() __builtin_amdgcn_sched_barrier(0)
#define VMWAIT(n) do { \
  asm volatile("s_waitcnt vmcnt(" #n ")" ::: "memory"); \
  __builtin_amdgcn_sched_barrier(0); \
} while (0)
#define LGKM0() do { \
  asm volatile("s_waitcnt lgkmcnt(0)" ::: "memory"); \
  __builtin_amdgcn_sched_barrier(0); \
} while (0)

// ---------------- prep 1: comb[b,o] = mean_l hidden @ Wh^T + bh + be ----------
__global__ void prep_comb_kernel(const float* __restrict__ hidden,
                                 const float* __restrict__ Wh,
                                 const float* __restrict__ bh,
                                 const float* __restrict__ be,
                                 float* __restrict__ comb) {
  __shared__ float hb[512];
  const int b = blockIdx.x, tid = threadIdx.x;  // 256 threads
  for (int i = tid; i < 512; i += 256)
    hb[i] = 0.5f * (hidden[b * 512 + i] + hidden[32768 + b * 512 + i]);
  __syncthreads();
  for (int o = tid; o < 512; o += 256) {
    const f32x4* wr = (const f32x4*)(Wh + o * 512);
    const f32x4* hv = (const f32x4*)hb;
    float s = 0.f;
    for (int k = 0; k < 128; ++k) {
      f32x4 w = wr[k], x = hv[k];
      s += w.x * x.x + w.y * x.y + w.z * x.z + w.w * x.w;
    }
    comb[b * 512 + o] = s + bh[o] + be[o];
  }
}

// ---------------- prep 2: pack We -> bf16 XOR-8 K-slice LDS images -----------
// Slice s (k0=s*64), 64KB: granule (o,g) g=0..7 at byte o*128 + ((g^(o&7))<<4),
// content bf16(We[o][s*64 + g*8 .. +8]).  (R1-verified scheme.)
__global__ void prep_pack_kernel(const float* __restrict__ We,
                                 unsigned short* __restrict__ wsw) {
  const int gid = blockIdx.x * 256 + threadIdx.x;  // 0..32767 granules
  const int s = gid >> 12;
  const int rem = gid & 4095;
  const int o = rem >> 3;
  const int gsw = rem & 7;
  const int g = gsw ^ (o & 7);
  const float* src = We + o * 512 + s * 64 + g * 8;
  u16x8 p;
#pragma unroll
  for (int e = 0; e < 8; ++e) p[e] = f2bf(src[e]);
  *(u16x8*)(wsw + (long)gid * 8) = p;
}

// ---------------- main: 8-phase fused GEMM + tanh + Wo-dot -> scores ---------
// grid 1024 (2 t's per block), 512 threads (8 waves: wm=wave>>2, wn=wave&3)
// block tile 128 x 512, BK=64 (8 steps), wave tile 64 rows x 128 cols.
__global__ __launch_bounds__(512, 2) void gemm_score_kernel(
    const float* __restrict__ enc,            // [T*B, 512] (row = t*64+b)
    const unsigned short* __restrict__ wsw,   // packed We (8 slices x 64KB)
    const float* __restrict__ comb,           // [64,512]
    const float* __restrict__ Wo,             // [512]
    float* __restrict__ scores)               // [64,2048]
{
  __shared__ __align__(16) unsigned char Blds[2][65536];  // 512 o x 64 k bf16 (swz)
  __shared__ __align__(16) unsigned char Alds[2][16384];  // 128 r x 64 k bf16 (swz)
  // spart overlaid on Alds after the K-loop.

  const int tid = threadIdx.x;
  const int lane = tid & 63;
  const int wave = tid >> 6;
  const int wm = wave >> 2;   // row half (64 rows)
  const int wn = wave & 3;    // col quarter (128 cols)
  const int l15 = lane & 15;
  const int lq = lane >> 4;   // 0..3

  const long r0 = (long)blockIdx.x * 128;

  // ---- A staging mapping: thread -> row = tid>>2, 16-float chunk aq = tid&3
  const int arow = tid >> 2;
  const int aq = tid & 3;
  const float* aglb = enc + (r0 + arow) * 512 + aq * 16;
  const int ag0 = aq * 2;  // first of two 8-bf16 granules
  const unsigned aw0 = (unsigned)(arow * 128 + (((ag0    ) ^ (arow & 7)) << 4));
  const unsigned aw1 = (unsigned)(arow * 128 + (((ag0 + 1) ^ (arow & 7)) << 4));

  const unsigned char* bglb = (const unsigned char*)wsw + (long)tid * 16;

  // ---- fragment read bases (XOR-8 swizzle; conflict <=2-way) ----
  const unsigned abase = (unsigned)((wm * 64 + l15) * 128);   // + m*2048
  const unsigned bbase = (unsigned)((wn * 128 + l15) * 128);  // + jn*2048
  const int osw = l15 & 7;

  f32x4 acc[4][8];
#pragma unroll
  for (int m = 0; m < 4; ++m)
#pragma unroll
    for (int j = 0; j < 8; ++j) acc[m][j] = (f32x4){0.f, 0.f, 0.f, 0.f};

#define STAGE_B(n)                                                             \
  {                                                                            \
    const unsigned char* bs_ = bglb + (long)(n) * 65536;                       \
    _Pragma("unroll")                                                          \
    for (int c = 0; c < 8; ++c)                                                \
      __builtin_amdgcn_global_load_lds((const AS1 unsigned int*)(bs_ + c * 8192), \
                                       (AS3 unsigned int*)(&Blds[(n) & 1][tid * 16 + c * 8192]), \
                                       16, 0, 0);                              \
  }

#define LOAD_A(n, dst)                                                         \
  {                                                                            \
    const float* as_ = aglb + (n) * 64;                                        \
    dst[0] = *(const f32x4*)(as_);                                             \
    dst[1] = *(const f32x4*)(as_ + 4);                                         \
    dst[2] = *(const f32x4*)(as_ + 8);                                         \
    dst[3] = *(const f32x4*)(as_ + 12);                                        \
  }

#define CVT_A(src, buf)                                                        \
  {                                                                            \
    u16x8 p0_, p1_;                                                            \
    p0_[0] = f2bf(src[0].x); p0_[1] = f2bf(src[0].y);                          \
    p0_[2] = f2bf(src[0].z); p0_[3] = f2bf(src[0].w);                          \
    p0_[4] = f2bf(src[1].x); p0_[5] = f2bf(src[1].y);                          \
    p0_[6] = f2bf(src[1].z); p0_[7] = f2bf(src[1].w);                          \
    p1_[0] = f2bf(src[2].x); p1_[1] = f2bf(src[2].y);                          \
    p1_[2] = f2bf(src[2].z); p1_[3] = f2bf(src[2].w);                          \
    p1_[4] = f2bf(src[3].x); p1_[5] = f2bf(src[3].y);                          \
    p1_[6] = f2bf(src[3].z); p1_[7] = f2bf(src[3].w);                          \
    *(u16x8*)(&Alds[buf][aw0]) = p0_;                                          \
    *(u16x8*)(&Alds[buf][aw1]) = p1_;                                          \
  }

  f32x4 a0t[4];
  f32x4 apre[2][4];

  // ---- prologue: issue A(0), B(0), A(1); VMWAIT(12) retires A(0) only ----
  LOAD_A(0, a0t)
  STAGE_B(0)
  LOAD_A(1, apre[1])
  SB();
  VMWAIT(12);                 // keep B(0):8 + A(1):4 in flight
  CVT_A(a0t, 0)
  LGKM0();

  // ---- main loop: 8 K-steps x 4 phases ----
#pragma unroll
  for (int t = 0; t < 8; ++t) {
    // step top
    if (t < 7) STAGE_B(t + 1)
    SB();
    if (t < 7) { VMWAIT(8); } else { VMWAIT(0); }   // retire B(t) + A(t+1) regs
    if (t < 7) CVT_A(apre[(t + 1) & 1], (t + 1) & 1)
    if (t + 2 < 8) LOAD_A(t + 2, apre[t & 1])
    SB();
    if (t < 7) LGKM0();       // publish A(t+1) ds_writes before next barrier

    const unsigned ab = abase + (unsigned)((t & 1) * 16384);
    const unsigned bb = bbase + (unsigned)((t & 1) * 65536);

#pragma unroll
    for (int ksub = 0; ksub < 2; ++ksub) {
      bf16x8 af0, af1, af2, af3;
      // ---- phase A (jn 0..3) ----
      __builtin_amdgcn_s_barrier();
      SB();
      af0 = *(const bf16x8*)(&Alds[0][ab + 0 * 2048 + (((ksub * 4 + lq) ^ osw) << 4)]);
      af1 = *(const bf16x8*)(&Alds[0][ab + 1 * 2048 + (((ksub * 4 + lq) ^ osw) << 4)]);
      af2 = *(const bf16x8*)(&Alds[0][ab + 2 * 2048 + (((ksub * 4 + lq) ^ osw) << 4)]);
      af3 = *(const bf16x8*)(&Alds[0][ab + 3 * 2048 + (((ksub * 4 + lq) ^ osw) << 4)]);
      {
        bf16x8 bf0 = *(const bf16x8*)(&Blds[0][bb + 0 * 2048 + (((ksub * 4 + lq) ^ osw) << 4)]);
        bf16x8 bf1 = *(const bf16x8*)(&Blds[0][bb + 1 * 2048 + (((ksub * 4 + lq) ^ osw) << 4)]);
        bf16x8 bf2 = *(const bf16x8*)(&Blds[0][bb + 2 * 2048 + (((ksub * 4 + lq) ^ osw) << 4)]);
        bf16x8 bf3 = *(const bf16x8*)(&Blds[0][bb + 3 * 2048 + (((ksub * 4 + lq) ^ osw) << 4)]);
        LGKM0();
        __builtin_amdgcn_s_setprio(1);
        acc[0][0] = __builtin_amdgcn_mfma_f32_16x16x32_bf16(af0, bf0, acc[0][0], 0, 0, 0);
        acc[1][0] = __builtin_amdgcn_mfma_f32_16x16x32_bf16(af1, bf0, acc[1][0], 0, 0, 0);
        acc[2][0] = __builtin_amdgcn_mfma_f32_16x16x32_bf16(af2, bf0, acc[2][0], 0, 0, 0);
        acc[3][0] = __builtin_amdgcn_mfma_f32_16x16x32_bf16(af3, bf0, acc[3][0], 0, 0, 0);
        acc[0][1] = __builtin_amdgcn_mfma_f32_16x16x32_bf16(af0, bf1, acc[0][1], 0, 0, 0);
        acc[1][1] = __builtin_amdgcn_mfma_f32_16x16x32_bf16(af1, bf1, acc[1][1], 0, 0, 0);
        acc[2][1] = __builtin_amdgcn_mfma_f32_16x16x32_bf16(af2, bf1, acc[2][1], 0, 0, 0);
        acc[3][1] = __builtin_amdgcn_mfma_f32_16x16x32_bf16(af3, bf1, acc[3][1], 0, 0, 0);
        acc[0][2] = __builtin_amdgcn_mfma_f32_16x16x32_bf16(af0, bf2, acc[0][2], 0, 0, 0);
        acc[1][2] = __builtin_amdgcn_mfma_f32_16x16x32_bf16(af1, bf2, acc[1][2], 0, 0, 0);
        acc[2][2] = __builtin_amdgcn_mfma_f32_16x16x32_bf16(af2, bf2, acc[2][2], 0, 0, 0);
        acc[3][2] = __builtin_amdgcn_mfma_f32_16x16x32_bf16(af3, bf2, acc[3][2], 0, 0, 0);
        acc[0][3] = __builtin_amdgcn_mfma_f32_16x16x32_bf16(af0, bf3, acc[0][3], 0, 0, 0);
        acc[1][3] = __builtin_amdgcn_mfma_f32_16x16x32_bf16(af1, bf3, acc[1][3], 0, 0, 0);
        acc[2][3] = __builtin_amdgcn_mfma_f32_16x16x32_bf16(af2, bf3, acc[2][3], 0, 0, 0);
        acc[3][3] = __builtin_amdgcn_mfma_f32_16x16x32_bf16(af3, bf3, acc[3][3], 0, 0, 0);
        __builtin_amdgcn_s_setprio(0);
      }
      // ---- phase B (jn 4..7) ----
      __builtin_amdgcn_s_barrier();
      SB();
      {
        bf16x8 bf4 = *(const bf16x8*)(&Blds[0][bb + 4 * 2048 + (((ksub * 4 + lq) ^ osw) << 4)]);
        bf16x8 bf5 = *(const bf16x8*)(&Blds[0][bb + 5 * 2048 + (((ksub * 4 + lq) ^ osw) << 4)]);
        bf16x8 bf6 = *(const bf16x8*)(&Blds[0][bb + 6 * 2048 + (((ksub * 4 + lq) ^ osw) << 4)]);
        bf16x8 bf7 = *(const bf16x8*)(&Blds[0][bb + 7 * 2048 + (((ksub * 4 + lq) ^ osw) << 4)]);
        LGKM0();
        __builtin_amdgcn_s_setprio(1);
        acc[0][4] = __builtin_amdgcn_mfma_f32_16x16x32_bf16(af0, bf4, acc[0][4], 0, 0, 0);
        acc[1][4] = __builtin_amdgcn_mfma_f32_16x16x32_bf16(af1, bf4, acc[1][4], 0, 0, 0);
        acc[2][4] = __builtin_amdgcn_mfma_f32_16x16x32_bf16(af2, bf4, acc[2][4], 0, 0, 0);
        acc[3][4] = __builtin_amdgcn_mfma_f32_16x16x32_bf16(af3, bf4, acc[3][4], 0, 0, 0);
        acc[0][5] = __builtin_amdgcn_mfma_f32_16x16x32_bf16(af0, bf5, acc[0][5], 0, 0, 0);
        acc[1][5] = __builtin_amdgcn_mfma_f32_16x16x32_bf16(af1, bf5, acc[1][5], 0, 0, 0);
        acc[2][5] = __builtin_amdgcn_mfma_f32_16x16x32_bf16(af2, bf5, acc[2][5], 0, 0, 0);
        acc[3][5] = __builtin_amdgcn_mfma_f32_16x16x32_bf16(af3, bf5, acc[3][5], 0, 0, 0);
        acc[0][6] = __builtin_amdgcn_mfma_f32_16x16x32_bf16(af0, bf6, acc[0][6], 0, 0, 0);
        acc[1][6] = __builtin_amdgcn_mfma_f32_16x16x32_bf16(af1, bf6, acc[1][6], 0, 0, 0);
        acc[2][6] = __builtin_amdgcn_mfma_f32_16x16x32_bf16(af2, bf6, acc[2][6], 0, 0, 0);
        acc[3][6] = __builtin_amdgcn_mfma_f32_16x16x32_bf16(af3, bf6, acc[3][6], 0, 0, 0);
        acc[0][7] = __builtin_amdgcn_mfma_f32_16x16x32_bf16(af0, bf7, acc[0][7], 0, 0, 0);
        acc[1][7] = __builtin_amdgcn_mfma_f32_16x16x32_bf16(af1, bf7, acc[1][7], 0, 0, 0);
        acc[2][7] = __builtin_amdgcn_mfma_f32_16x16x32_bf16(af2, bf7, acc[2][7], 0, 0, 0);
        acc[3][7] = __builtin_amdgcn_mfma_f32_16x16x32_bf16(af3, bf7, acc[3][7], 0, 0, 0);
        __builtin_amdgcn_s_setprio(0);
      }
    }
  }
#undef STAGE_B
#undef LOAD_A
#undef CVT_A

  // ---- fused epilogue: tanh(acc + comb[b,col]) * Wo[col], reduce over cols ----
  // D frag: local row = wm*64 + m*16 + lq*4 + q; b = row&63; t = bid*2 + row>>6;
  // col = wn*128 + jn*16 + l15.
  __syncthreads();
  float* spart = (float*)&Alds[0][0];  // [4][128] overlay (Alds dead)

  float wo[8];
#pragma unroll
  for (int jn = 0; jn < 8; ++jn) wo[jn] = Wo[wn * 128 + jn * 16 + l15];

#pragma unroll
  for (int m = 0; m < 4; ++m) {
#pragma unroll
    for (int q = 0; q < 4; ++q) {
      const int row = wm * 64 + m * 16 + lq * 4 + q;  // 0..127
      const float* crow = comb + (row & 63) * 512;
      float s = 0.f;
#pragma unroll
      for (int jn = 0; jn < 8; ++jn) {
        const int col = wn * 128 + jn * 16 + l15;
        const float x = acc[m][jn][q] + crow[col];
        s += fast_tanh(x) * wo[jn];
      }
      s += __shfl_xor(s, 1, 16);
      s += __shfl_xor(s, 2, 16);
      s += __shfl_xor(s, 4, 16);
      s += __shfl_xor(s, 8, 16);
      if (l15 == 0) spart[wn * 128 + row] = s;
    }
  }
  __syncthreads();
  if (tid < 128) {
    const float s = spart[tid] + spart[128 + tid] + spart[256 + tid] + spart[384 + tid];
    const int b = tid & 63;
    const long tt = (long)blockIdx.x * 2 + (tid >> 6);
    scores[(long)b * 2048 + tt] = s;
  }
}

// ---------------- masked softmax over valid prefix ---------------------------
__global__ void softmax_kernel(const float* __restrict__ scores,
                               const int* __restrict__ enc_len,
                               float* __restrict__ out) {
  const int b = blockIdx.x;
  const int tid = threadIdx.x;  // 256
  const int lane = tid & 63;
  const int wv = tid >> 6;
  __shared__ float red[4];
  const int n = enc_len[b];
  const float* sc = scores + (long)b * 2048;

  float v[8];
  float m = -1e30f;
#pragma unroll
  for (int j = 0; j < 8; ++j) {
    const int t = tid + j * 256;
    v[j] = sc[t];
    if (t < n) m = fmaxf(m, v[j]);
  }
#pragma unroll
  for (int k = 32; k; k >>= 1) m = fmaxf(m, __shfl_xor(m, k, 64));
  if (lane == 0) red[wv] = m;
  __syncthreads();
  m = fmaxf(fmaxf(red[0], red[1]), fmaxf(red[2], red[3]));
  __syncthreads();

  float s = 0.f;
#pragma unroll
  for (int j = 0; j < 8; ++j) {
    const int t = tid + j * 256;
    const float e = (t < n) ? __expf(v[j] - m) : 0.f;
    v[j] = e;
    s += e;
  }
#pragma unroll
  for (int k = 32; k; k >>= 1) s += __shfl_xor(s, k, 64);
  if (lane == 0) red[wv] = s;
  __syncthreads();
  s = red[0] + red[1] + red[2] + red[3];
  const float inv = 1.0f / s;
#pragma unroll
  for (int j = 0; j < 8; ++j) {
    const int t = tid + j * 256;
    out[(long)b * 2048 + t] = v[j] * inv;
  }
}

extern "C" void kernel_launch(void* const* d_in, const int* in_sizes, int n_in,
                              void* d_out, int out_size, void* d_ws, size_t ws_size,
                              hipStream_t stream) {
  const float* hidden = (const float*)d_in[0];   // [2,64,512]
  const float* enc    = (const float*)d_in[1];   // [2048,64,512]
  const int*   enclen = (const int*)d_in[2];     // [64]
  const float* Wh     = (const float*)d_in[3];   // [512,512]
  const float* bh     = (const float*)d_in[4];   // [512]
  const float* We     = (const float*)d_in[5];   // [512,512]
  const float* be     = (const float*)d_in[6];   // [512]
  const float* Wo     = (const float*)d_in[7];   // [512]
  // d_in[8] = bo: softmax-invariant, dropped
  float* out = (float*)d_out;

  uint8_t* ws = (uint8_t*)d_ws;
  unsigned short* wsw = (unsigned short*)ws;             // 512 KB
  float* comb   = (float*)(ws + 524288);                 // 128 KB
  float* scores = (float*)(ws + 524288 + 131072);        // 512 KB

  hipLaunchKernelGGL(prep_comb_kernel, dim3(64), dim3(256), 0, stream,
                     hidden, Wh, bh, be, comb);
  hipLaunchKernelGGL(prep_pack_kernel, dim3(128), dim3(256), 0, stream, We, wsw);
  hipLaunchKernelGGL(gemm_score_kernel, dim3(1024), dim3(512), 0, stream,
                     enc, wsw, comb, Wo, scores);
  hipLaunchKernelGGL(softmax_kernel, dim3(64), dim3(256), 0, stream,
                     scores, enclen, out);
}